// Round 20
// baseline (381.311 us; speedup 1.0000x reference)
//
#include <hip/hip_runtime.h>
#include <hip/hip_bf16.h>

#define NN 6607
#define HH 64
#define TT 3
#define EE 1000000
#define KSH 50                 // shards per type; EE/KSH = 20000 (even -> int2 aligned)

typedef __attribute__((ext_vector_type(8))) short bf16x8;
typedef __attribute__((ext_vector_type(4))) short short4v;
typedef __attribute__((ext_vector_type(4))) float f32x4;
typedef __attribute__((ext_vector_type(4))) int i32x4;

// LDS-only barrier: orders LDS ops across the block WITHOUT draining vmem.
#define LGKM_BARRIER() do { \
    __builtin_amdgcn_sched_barrier(0); \
    asm volatile("s_waitcnt lgkmcnt(0)" ::: "memory"); \
    __builtin_amdgcn_s_barrier(); \
    __builtin_amdgcn_sched_barrier(0); \
} while (0)

// ---------------- fused prep + pass1 histogram ----------------

__global__ void prep_hist_kernel(const float* __restrict__ wrec, short* __restrict__ wrecb,
                                 const float* __restrict__ emb, float* __restrict__ o_xinit,
                                 short* __restrict__ embb,
                                 const int* __restrict__ ei, unsigned short* __restrict__ H) {
    if (blockIdx.x < KSH * TT) {
        int k = blockIdx.x % KSH, t = blockIdx.x / KSH;
        __shared__ int h[NN];
        for (int i = threadIdx.x; i < NN; i += 1024) h[i] = 0;
        __syncthreads();
        const int2* d2 = (const int2*)(ei + t * 2 * EE + EE + k * (EE / KSH));
        for (int i = threadIdx.x; i < (EE / KSH) / 2; i += 1024) {
            int2 p = d2[i];
            atomicAdd(&h[p.x], 1);
            atomicAdd(&h[p.y], 1);
        }
        __syncthreads();
        unsigned short* Ht = H + (size_t)(t * KSH + k) * NN;
        for (int i = threadIdx.x; i < NN; i += 1024) Ht[i] = (unsigned short)h[i];
    } else {
        int i = (blockIdx.x - KSH * TT) * 1024 + threadIdx.x;
        if (i < 105712) {                      // emb: copy f32 + convert bf16
            f32x4 v = ((const f32x4*)emb)[i];
            ((f32x4*)o_xinit)[i] = v;
            short4v s;
            s[0] = (short)__bfloat16_as_ushort(__float2bfloat16(v[0]));
            s[1] = (short)__bfloat16_as_ushort(__float2bfloat16(v[1]));
            s[2] = (short)__bfloat16_as_ushort(__float2bfloat16(v[2]));
            s[3] = (short)__bfloat16_as_ushort(__float2bfloat16(v[3]));
            ((short4v*)embb)[i] = s;
        }
        if (i < 317136) {
            f32x4 v = ((const f32x4*)wrec)[i];
            short4v s;
            s[0] = (short)__bfloat16_as_ushort(__float2bfloat16(v[0]));
            s[1] = (short)__bfloat16_as_ushort(__float2bfloat16(v[1]));
            s[2] = (short)__bfloat16_as_ushort(__float2bfloat16(v[2]));
            s[3] = (short)__bfloat16_as_ushort(__float2bfloat16(v[3]));
            ((short4v*)wrecb)[i] = s;
        }
    }
}

// pass2a: per node, exclusive-scan H over shards (in place, u16) -> degI.
__global__ void off2a_kernel(unsigned short* __restrict__ H, int* __restrict__ degI) {
    int t = blockIdx.y;
    int i = blockIdx.x * 256 + threadIdx.x;
    if (i >= NN) return;
    int run = 0;
    #pragma unroll
    for (int k = 0; k < KSH; ++k) {
        unsigned short* p = H + (size_t)(t * KSH + k) * NN + i;
        int v = *p; *p = (unsigned short)run; run += v;
    }
    degI[t * NN + i] = run;
}

// pass2b: per-type exclusive scan over nodes -> basep.
__global__ void off2b_kernel(const int* __restrict__ degI, int* __restrict__ basep) {
    int t = blockIdx.x;
    int lane = threadIdx.x;  // 64 threads
    const int* d = degI + t * NN;
    int* bp = basep + t * NN;
    int carry = 0;
    for (int b0 = 0; b0 < NN; b0 += 64) {
        int i = b0 + lane;
        int v = (i < NN) ? d[i] : 0;
        int s = v;
        #pragma unroll
        for (int off = 1; off < 64; off <<= 1) {
            int u = __shfl_up(s, off, 64);
            if (lane >= off) s += u;
        }
        if (i < NN) bp[i] = carry + s - v;
        carry += __shfl(s, 63, 64);
    }
}

// pass3: LDS cursor; csr stored as u16 (node ids < 6607) -> half the scatter bytes.
__global__ void fill3_kernel(const int* __restrict__ ei, const unsigned short* __restrict__ H,
                             const int* __restrict__ basep, unsigned short* __restrict__ csr) {
    int k = blockIdx.x, t = blockIdx.y;
    __shared__ int cur[NN];
    const unsigned short* Ht = H + (size_t)(t * KSH + k) * NN;
    const int* bp = basep + t * NN;
    for (int i = threadIdx.x; i < NN; i += 1024) cur[i] = bp[i] + (int)Ht[i];
    __syncthreads();
    const int2* s2 = (const int2*)(ei + t * 2 * EE + k * (EE / KSH));
    const int2* d2 = (const int2*)(ei + t * 2 * EE + EE + k * (EE / KSH));
    unsigned short* cs = csr + (size_t)t * EE;
    for (int i = threadIdx.x; i < (EE / KSH) / 2; i += 1024) {
        int2 d = d2[i], s = s2[i];
        int p0 = atomicAdd(&cur[d.x], 1);
        cs[p0] = (unsigned short)s.x;
        int p1 = atomicAdd(&cur[d.y], 1);
        cs[p1] = (unsigned short)s.y;
    }
}

// ---------------- SAGE layer (bf16 gather, 16-edge unroll = 8 outstanding/half) ----------------

template <int LAYER>
__global__ void __launch_bounds__(512) sage_kernel(
        const unsigned int* __restrict__ xb_all,   // bf16x2 rows, stride 32 uints
        const int* __restrict__ basep, const int* __restrict__ degI,
        const unsigned short* __restrict__ csr,
        const float* __restrict__ W_l, const float* __restrict__ b_l,
        const float* __restrict__ W_r,
        float* __restrict__ yf, unsigned short* __restrict__ yb) {
    int t = blockIdx.y;
    __shared__ float wl[64][68];
    __shared__ float wr[64][68];
    __shared__ float mean_s[8][64];
    __shared__ float xi_s[8][64];
    const f32x4* Wl4 = (const f32x4*)(W_l + t * 4096);
    const f32x4* Wr4 = (const f32x4*)(W_r + t * 4096);
    for (int cc = threadIdx.x; cc < 1024; cc += 512) {
        int h = cc >> 4, k = (cc & 15) << 2;
        *(f32x4*)&wl[h][k] = Wl4[cc];
        *(f32x4*)&wr[h][k] = Wr4[cc];
    }
    __syncthreads();

    int lane = threadIdx.x & 63;
    int widx = threadIdx.x >> 6;   // 0..7
    int i = blockIdx.x * 8 + widx;
    if (i >= NN) return;

    const unsigned int* xb = xb_all + (LAYER == 2 ? (size_t)t * NN * 32 : 0);
    int rp0 = basep[t * NN + i];
    int d = degI[t * NN + i];
    int rp1 = rp0 + d;
    const unsigned short* cs = csr + (size_t)t * EE;

    int h2 = lane >> 5;
    int c = lane & 31;   // uint index: channels 2c (lo), 2c+1 (hi)

    float a0l = 0.f, a0h = 0.f, a1l = 0.f, a1h = 0.f;
    float a2l = 0.f, a2h = 0.f, a3l = 0.f, a3h = 0.f;
    int e = rp0;
    if ((e & 1) && e < rp1) {
        if (h2 == 0) {
            unsigned u = xb[(size_t)cs[e] * 32 + c];
            a0l += __uint_as_float(u << 16);
            a0h += __uint_as_float(u & 0xffff0000u);
        }
        ++e;
    }
    for (; e + 16 <= rp1; e += 16) {
        const ushort2* q = (const ushort2*)(cs + e) + 4 * h2;
        ushort2 p0 = q[0], p1 = q[1], p2 = q[2], p3 = q[3];
        unsigned u0 = xb[(size_t)p0.x * 32 + c];
        unsigned u1 = xb[(size_t)p0.y * 32 + c];
        unsigned u2 = xb[(size_t)p1.x * 32 + c];
        unsigned u3 = xb[(size_t)p1.y * 32 + c];
        unsigned u4 = xb[(size_t)p2.x * 32 + c];
        unsigned u5 = xb[(size_t)p2.y * 32 + c];
        unsigned u6 = xb[(size_t)p3.x * 32 + c];
        unsigned u7 = xb[(size_t)p3.y * 32 + c];
        a0l += __uint_as_float(u0 << 16); a0h += __uint_as_float(u0 & 0xffff0000u);
        a1l += __uint_as_float(u1 << 16); a1h += __uint_as_float(u1 & 0xffff0000u);
        a2l += __uint_as_float(u2 << 16); a2h += __uint_as_float(u2 & 0xffff0000u);
        a3l += __uint_as_float(u3 << 16); a3h += __uint_as_float(u3 & 0xffff0000u);
        a0l += __uint_as_float(u4 << 16); a0h += __uint_as_float(u4 & 0xffff0000u);
        a1l += __uint_as_float(u5 << 16); a1h += __uint_as_float(u5 & 0xffff0000u);
        a2l += __uint_as_float(u6 << 16); a2h += __uint_as_float(u6 & 0xffff0000u);
        a3l += __uint_as_float(u7 << 16); a3h += __uint_as_float(u7 & 0xffff0000u);
    }
    for (; e + 8 <= rp1; e += 8) {
        const ushort2* q = (const ushort2*)(cs + e) + 2 * h2;
        ushort2 p0 = q[0], p1 = q[1];
        unsigned u0 = xb[(size_t)p0.x * 32 + c];
        unsigned u1 = xb[(size_t)p0.y * 32 + c];
        unsigned u2 = xb[(size_t)p1.x * 32 + c];
        unsigned u3 = xb[(size_t)p1.y * 32 + c];
        a0l += __uint_as_float(u0 << 16); a0h += __uint_as_float(u0 & 0xffff0000u);
        a1l += __uint_as_float(u1 << 16); a1h += __uint_as_float(u1 & 0xffff0000u);
        a2l += __uint_as_float(u2 << 16); a2h += __uint_as_float(u2 & 0xffff0000u);
        a3l += __uint_as_float(u3 << 16); a3h += __uint_as_float(u3 & 0xffff0000u);
    }
    float al = (a0l + a1l) + (a2l + a3l);
    float ah = (a0h + a1h) + (a2h + a3h);
    if (h2 == 0) {
        for (; e < rp1; ++e) {
            unsigned u = xb[(size_t)cs[e] * 32 + c];
            al += __uint_as_float(u << 16);
            ah += __uint_as_float(u & 0xffff0000u);
        }
    }
    al += __shfl_xor(al, 32, 64);
    ah += __shfl_xor(ah, 32, 64);

    float inv = 1.f / (float)(d > 1 ? d : 1);
    if (h2 == 0) {
        unsigned uxi = xb[(size_t)i * 32 + c];
        mean_s[widx][2 * c]     = al * inv;
        mean_s[widx][2 * c + 1] = ah * inv;
        xi_s[widx][2 * c]     = __uint_as_float(uxi << 16);
        xi_s[widx][2 * c + 1] = __uint_as_float(uxi & 0xffff0000u);
    }

    float out = b_l[t * 64 + lane];
    #pragma unroll 4
    for (int k0 = 0; k0 < 64; k0 += 4) {
        f32x4 m4 = *(const f32x4*)&mean_s[widx][k0];
        f32x4 x4 = *(const f32x4*)&xi_s[widx][k0];
        f32x4 l4 = *(const f32x4*)&wl[lane][k0];
        f32x4 r4 = *(const f32x4*)&wr[lane][k0];
        out += m4[0] * l4[0] + m4[1] * l4[1] + m4[2] * l4[2] + m4[3] * l4[3];
        out += x4[0] * r4[0] + x4[1] * r4[1] + x4[2] * r4[2] + x4[3] * r4[3];
    }
    out = fmaxf(out, 0.f);
    if (LAYER == 1) {
        yb[(size_t)t * NN * HH + (size_t)i * 64 + lane] =
            __bfloat16_as_ushort(__float2bfloat16(out));
    } else {
        yf[(size_t)t * NN * HH + (size_t)i * 64 + lane] = out;
    }
}

// ---------------- reconstruction: recon[t] = h2[t] @ Wrec[t]^T + brec[t] ----------------
// Write-locality build: PLAIN stores (L2 write-combining) + bijective XCD swizzle
// (m204) with column-group fastest -> each XCD owns a contiguous ~65MB advancing
// output window; its L2 writebacks become long sequential HBM streams.
// (nt-stores bypass L2 and made block order irrelevant — untested combination.)

__global__ void __launch_bounds__(256) recon_kernel(
        const float* __restrict__ h2f, const short* __restrict__ wrecb,
        const float* __restrict__ brec, float* __restrict__ out) {
    constexpr int NI = (NN + 15) / 16;   // 413 strips
    constexpr int NG = 7;                // col-groups of 1024
    constexpr int NWG = NI * NG * TT;    // 8673
    constexpr int NX = 8;                // XCDs
    constexpr int Q = NWG / NX;          // 1084
    constexpr int R = NWG % NX;          // 1
    __shared__ float buf[16][260];

    // bijective XCD swizzle: XCD x (= bid%8) processes a contiguous work-id chunk
    int bid = blockIdx.x;
    int xcd = bid % NX;
    int idx = bid / NX;
    int work = (xcd < R ? xcd * (Q + 1) : R * (Q + 1) + (xcd - R) * Q) + idx;

    // decompose with jg FASTEST -> consecutive work-ids advance columns within a strip
    int t = work / (NI * NG);
    int rem = work % (NI * NG);
    int it = rem / NG;
    int jg = rem % NG;
    int i0 = it * 16;
    int colbase = jg * 1024;
    int nch = (NN - colbase + 255) / 256;
    if (nch > 4) nch = 4;

    int tid = threadIdx.x;
    int lane = tid & 63;
    int w = tid >> 6;
    int r = lane & 15;
    int kb = (lane >> 4) * 8;
    int rbase = (lane >> 4) * 4;

    const float* A = h2f + (size_t)t * NN * HH;
    const short* B = wrecb + (size_t)t * NN * HH;
    const float* br = brec + t * NN;
    size_t obase = (size_t)t * NN * NN;

    f32x4 af0 = *(const f32x4*)(A + (size_t)(i0 + r) * 64 + kb);
    f32x4 af1 = *(const f32x4*)(A + (size_t)(i0 + r) * 64 + kb + 4);
    f32x4 af2 = *(const f32x4*)(A + (size_t)(i0 + r) * 64 + kb + 32);
    f32x4 af3 = *(const f32x4*)(A + (size_t)(i0 + r) * 64 + kb + 36);
    bf16x8 a0, a1;
    #pragma unroll
    for (int q = 0; q < 4; ++q) {
        a0[q]     = (short)__bfloat16_as_ushort(__float2bfloat16(af0[q]));
        a0[q + 4] = (short)__bfloat16_as_ushort(__float2bfloat16(af1[q]));
        a1[q]     = (short)__bfloat16_as_ushort(__float2bfloat16(af2[q]));
        a1[q + 4] = (short)__bfloat16_as_ushort(__float2bfloat16(af3[q]));
    }

    int scol = lane << 2;

    bf16x8 Breg[8];
    float biasreg[4];

    auto loadB = [&](int chunk) {
        int jbase = colbase + chunk * 256 + w * 64;
        #pragma unroll
        for (int jt = 0; jt < 4; ++jt) {
            int j0 = jbase + jt * 16;
            Breg[2 * jt]     = *(const bf16x8*)(B + (size_t)(j0 + r) * 64 + kb);
            Breg[2 * jt + 1] = *(const bf16x8*)(B + (size_t)(j0 + r) * 64 + kb + 32);
            int col = j0 + r;
            col = col < NN ? col : NN - 1;
            biasreg[jt] = br[col];
        }
    };

    auto mfma_phase = [&]() {
        #pragma unroll
        for (int jt = 0; jt < 4; ++jt) {
            float bb = biasreg[jt];
            f32x4 acc = {bb, bb, bb, bb};
            acc = __builtin_amdgcn_mfma_f32_16x16x32_bf16(a0, Breg[2 * jt], acc, 0, 0, 0);
            acc = __builtin_amdgcn_mfma_f32_16x16x32_bf16(a1, Breg[2 * jt + 1], acc, 0, 0, 0);
            int jloc = w * 64 + jt * 16 + r;
            #pragma unroll
            for (int q = 0; q < 4; ++q) buf[rbase + q][jloc] = acc[q];
        }
    };

    auto store_phase = [&](int chunk) {
        int colg = colbase + chunk * 256 + scol;
        if (colg >= NN) return;
        bool full4 = (colg + 4 <= NN);
        #pragma unroll
        for (int p = 0; p < 4; ++p) {
            int rloc = p * 4 + w;
            int row = i0 + rloc;
            if (row >= NN) continue;
            f32x4 v = *(const f32x4*)&buf[rloc][scol];
            float* pp = out + obase + (size_t)row * NN + colg;
            if (full4) {
                *(f32x4*)pp = v;                       // plain: L2 write-combining
            } else {
                pp[0] = v[0];
                if (colg + 1 < NN) pp[1] = v[1];
                if (colg + 2 < NN) pp[2] = v[2];
            }
        }
    };

    loadB(0);
    mfma_phase();
    LGKM_BARRIER();
    for (int cch = 1; cch < nch; ++cch) {
        loadB(cch);
        store_phase(cch - 1);
        LGKM_BARRIER();
        mfma_phase();
        LGKM_BARRIER();
    }
    store_phase(nch - 1);
}

// ---------------- launch ----------------

extern "C" void kernel_launch(void* const* d_in, const int* in_sizes, int n_in,
                              void* d_out, int out_size, void* d_ws, size_t ws_size,
                              hipStream_t stream) {
    const float* emb  = (const float*)d_in[0];
    const int*   ei   = (const int*)d_in[1];
    const float* W1l  = (const float*)d_in[2];
    const float* b1   = (const float*)d_in[3];
    const float* W1r  = (const float*)d_in[4];
    const float* W2l  = (const float*)d_in[5];
    const float* b2   = (const float*)d_in[6];
    const float* W2r  = (const float*)d_in[7];
    const float* Wrec = (const float*)d_in[8];
    const float* brec = (const float*)d_in[9];

    char* ws = (char*)d_ws;
    int*            degI  = (int*)(ws + 0);            // 79284 -> pad 79296
    int*            basep = (int*)(ws + 79296);        // 79284 -> pad 79296
    unsigned short* csrb  = (unsigned short*)(ws + 158592);   // 6000000 -> 6158592
    unsigned short* H     = (unsigned short*)(ws + 6158592);  // 1982100 -> pad 1982208 -> 8140800
    unsigned short* h1b   = (unsigned short*)(ws + 8140800);  // 2537088 -> 10677888
    short*          embb  = (short*)(ws + 10677888);   // 845696 -> 11523584
    short*          wrecb = (short*)(ws + 11523584);   // 2545280 -> 14068864

    float* o_emb   = (float*)d_out;                        // [T][N][H]
    float* o_recon = o_emb + (size_t)TT * NN * HH;         // [T][N][N]
    float* o_xinit = o_recon + (size_t)TT * NN * NN;       // [N][H]

    int phgrid = KSH * TT + (317136 + 1023) / 1024;   // 150 hist + 310 prep
    prep_hist_kernel<<<phgrid, 1024, 0, stream>>>(Wrec, wrecb, emb, o_xinit, embb, ei, H);
    dim3 o2grid((NN + 255) / 256, TT);                // 26 x 3
    off2a_kernel<<<o2grid, 256, 0, stream>>>(H, degI);
    off2b_kernel<<<TT, 64, 0, stream>>>(degI, basep);
    dim3 fgrid(KSH, TT);
    fill3_kernel<<<fgrid, 1024, 0, stream>>>(ei, H, basep, csrb);

    dim3 sgrid((NN + 7) / 8, TT);                     // 826 x 3, 512-thread blocks
    sage_kernel<1><<<sgrid, 512, 0, stream>>>((const unsigned int*)embb, basep, degI, csrb,
                                              W1l, b1, W1r, nullptr, h1b);
    sage_kernel<2><<<sgrid, 512, 0, stream>>>((const unsigned int*)h1b, basep, degI, csrb,
                                              W2l, b2, W2r, o_emb, nullptr);

    constexpr int NI = (NN + 15) / 16;   // 413
    constexpr int NG = 7;
    int rblocks = NI * NG * TT;          // 8673
    recon_kernel<<<rblocks, 256, 0, stream>>>(o_emb, wrecb, brec, o_recon);
}

// Round 21
// 338.343 us; speedup vs baseline: 1.1270x; 1.1270x over previous
//
#include <hip/hip_runtime.h>
#include <hip/hip_bf16.h>

#define NN 6607
#define HH 64
#define TT 3
#define EE 1000000
#define KSH 50                 // shards per type; EE/KSH = 20000 (even -> int2 aligned)

typedef __attribute__((ext_vector_type(8))) short bf16x8;
typedef __attribute__((ext_vector_type(4))) short short4v;
typedef __attribute__((ext_vector_type(4))) float f32x4;
typedef __attribute__((ext_vector_type(4))) int i32x4;

// LDS-only barrier: orders LDS ops across the block WITHOUT draining vmem.
#define LGKM_BARRIER() do { \
    __builtin_amdgcn_sched_barrier(0); \
    asm volatile("s_waitcnt lgkmcnt(0)" ::: "memory"); \
    __builtin_amdgcn_s_barrier(); \
    __builtin_amdgcn_sched_barrier(0); \
} while (0)

// ---------------- fused prep + pass1 histogram ----------------

__global__ void prep_hist_kernel(const float* __restrict__ wrec, short* __restrict__ wrecb,
                                 const float* __restrict__ emb, float* __restrict__ o_xinit,
                                 short* __restrict__ embb,
                                 const int* __restrict__ ei, unsigned short* __restrict__ H) {
    if (blockIdx.x < KSH * TT) {
        int k = blockIdx.x % KSH, t = blockIdx.x / KSH;
        __shared__ int h[NN];
        for (int i = threadIdx.x; i < NN; i += 1024) h[i] = 0;
        __syncthreads();
        const int2* d2 = (const int2*)(ei + t * 2 * EE + EE + k * (EE / KSH));
        for (int i = threadIdx.x; i < (EE / KSH) / 2; i += 1024) {
            int2 p = d2[i];
            atomicAdd(&h[p.x], 1);
            atomicAdd(&h[p.y], 1);
        }
        __syncthreads();
        unsigned short* Ht = H + (size_t)(t * KSH + k) * NN;
        for (int i = threadIdx.x; i < NN; i += 1024) Ht[i] = (unsigned short)h[i];
    } else {
        int i = (blockIdx.x - KSH * TT) * 1024 + threadIdx.x;
        if (i < 105712) {                      // emb: copy f32 + convert bf16
            f32x4 v = ((const f32x4*)emb)[i];
            ((f32x4*)o_xinit)[i] = v;
            short4v s;
            s[0] = (short)__bfloat16_as_ushort(__float2bfloat16(v[0]));
            s[1] = (short)__bfloat16_as_ushort(__float2bfloat16(v[1]));
            s[2] = (short)__bfloat16_as_ushort(__float2bfloat16(v[2]));
            s[3] = (short)__bfloat16_as_ushort(__float2bfloat16(v[3]));
            ((short4v*)embb)[i] = s;
        }
        if (i < 317136) {
            f32x4 v = ((const f32x4*)wrec)[i];
            short4v s;
            s[0] = (short)__bfloat16_as_ushort(__float2bfloat16(v[0]));
            s[1] = (short)__bfloat16_as_ushort(__float2bfloat16(v[1]));
            s[2] = (short)__bfloat16_as_ushort(__float2bfloat16(v[2]));
            s[3] = (short)__bfloat16_as_ushort(__float2bfloat16(v[3]));
            ((short4v*)wrecb)[i] = s;
        }
    }
}

// pass2a: per node, exclusive-scan H over shards (in place, u16) -> degI.
__global__ void off2a_kernel(unsigned short* __restrict__ H, int* __restrict__ degI) {
    int t = blockIdx.y;
    int i = blockIdx.x * 256 + threadIdx.x;
    if (i >= NN) return;
    int run = 0;
    #pragma unroll
    for (int k = 0; k < KSH; ++k) {
        unsigned short* p = H + (size_t)(t * KSH + k) * NN + i;
        int v = *p; *p = (unsigned short)run; run += v;
    }
    degI[t * NN + i] = run;
}

// pass2b: per-type exclusive scan over nodes -> basep.
__global__ void off2b_kernel(const int* __restrict__ degI, int* __restrict__ basep) {
    int t = blockIdx.x;
    int lane = threadIdx.x;  // 64 threads
    const int* d = degI + t * NN;
    int* bp = basep + t * NN;
    int carry = 0;
    for (int b0 = 0; b0 < NN; b0 += 64) {
        int i = b0 + lane;
        int v = (i < NN) ? d[i] : 0;
        int s = v;
        #pragma unroll
        for (int off = 1; off < 64; off <<= 1) {
            int u = __shfl_up(s, off, 64);
            if (lane >= off) s += u;
        }
        if (i < NN) bp[i] = carry + s - v;
        carry += __shfl(s, 63, 64);
    }
}

// pass3: LDS cursor; csr stored as u16 (node ids < 6607) -> half the scatter bytes.
__global__ void fill3_kernel(const int* __restrict__ ei, const unsigned short* __restrict__ H,
                             const int* __restrict__ basep, unsigned short* __restrict__ csr) {
    int k = blockIdx.x, t = blockIdx.y;
    __shared__ int cur[NN];
    const unsigned short* Ht = H + (size_t)(t * KSH + k) * NN;
    const int* bp = basep + t * NN;
    for (int i = threadIdx.x; i < NN; i += 1024) cur[i] = bp[i] + (int)Ht[i];
    __syncthreads();
    const int2* s2 = (const int2*)(ei + t * 2 * EE + k * (EE / KSH));
    const int2* d2 = (const int2*)(ei + t * 2 * EE + EE + k * (EE / KSH));
    unsigned short* cs = csr + (size_t)t * EE;
    for (int i = threadIdx.x; i < (EE / KSH) / 2; i += 1024) {
        int2 d = d2[i], s = s2[i];
        int p0 = atomicAdd(&cur[d.x], 1);
        cs[p0] = (unsigned short)s.x;
        int p1 = atomicAdd(&cur[d.y], 1);
        cs[p1] = (unsigned short)s.y;
    }
}

// ---------------- SAGE layer (bf16 gather, 16-edge unroll = 8 outstanding/half) ----------------
// LAYER 1: x = embb (shared across types), out -> h1b (bf16)
// LAYER 2: x = h1b[t], out -> o_emb (f32)

template <int LAYER>
__global__ void __launch_bounds__(512) sage_kernel(
        const unsigned int* __restrict__ xb_all,   // bf16x2 rows, stride 32 uints
        const int* __restrict__ basep, const int* __restrict__ degI,
        const unsigned short* __restrict__ csr,
        const float* __restrict__ W_l, const float* __restrict__ b_l,
        const float* __restrict__ W_r,
        float* __restrict__ yf, unsigned short* __restrict__ yb) {
    int t = blockIdx.y;
    __shared__ float wl[64][68];
    __shared__ float wr[64][68];
    __shared__ float mean_s[8][64];
    __shared__ float xi_s[8][64];
    const f32x4* Wl4 = (const f32x4*)(W_l + t * 4096);
    const f32x4* Wr4 = (const f32x4*)(W_r + t * 4096);
    for (int cc = threadIdx.x; cc < 1024; cc += 512) {
        int h = cc >> 4, k = (cc & 15) << 2;
        *(f32x4*)&wl[h][k] = Wl4[cc];
        *(f32x4*)&wr[h][k] = Wr4[cc];
    }
    __syncthreads();

    int lane = threadIdx.x & 63;
    int widx = threadIdx.x >> 6;   // 0..7
    int i = blockIdx.x * 8 + widx;
    if (i >= NN) return;

    const unsigned int* xb = xb_all + (LAYER == 2 ? (size_t)t * NN * 32 : 0);
    int rp0 = basep[t * NN + i];
    int d = degI[t * NN + i];
    int rp1 = rp0 + d;
    const unsigned short* cs = csr + (size_t)t * EE;

    int h2 = lane >> 5;
    int c = lane & 31;   // uint index: channels 2c (lo), 2c+1 (hi)

    float a0l = 0.f, a0h = 0.f, a1l = 0.f, a1h = 0.f;
    float a2l = 0.f, a2h = 0.f, a3l = 0.f, a3h = 0.f;
    int e = rp0;
    if ((e & 1) && e < rp1) {
        if (h2 == 0) {
            unsigned u = xb[(size_t)cs[e] * 32 + c];
            a0l += __uint_as_float(u << 16);
            a0h += __uint_as_float(u & 0xffff0000u);
        }
        ++e;
    }
    // 16 edges/iter: half-wave h2 takes 8 edges -> 8 gathers in flight (2x MLP)
    for (; e + 16 <= rp1; e += 16) {
        const ushort2* q = (const ushort2*)(cs + e) + 4 * h2;   // 4B-aligned (e even)
        ushort2 p0 = q[0], p1 = q[1], p2 = q[2], p3 = q[3];
        unsigned u0 = xb[(size_t)p0.x * 32 + c];
        unsigned u1 = xb[(size_t)p0.y * 32 + c];
        unsigned u2 = xb[(size_t)p1.x * 32 + c];
        unsigned u3 = xb[(size_t)p1.y * 32 + c];
        unsigned u4 = xb[(size_t)p2.x * 32 + c];
        unsigned u5 = xb[(size_t)p2.y * 32 + c];
        unsigned u6 = xb[(size_t)p3.x * 32 + c];
        unsigned u7 = xb[(size_t)p3.y * 32 + c];
        a0l += __uint_as_float(u0 << 16); a0h += __uint_as_float(u0 & 0xffff0000u);
        a1l += __uint_as_float(u1 << 16); a1h += __uint_as_float(u1 & 0xffff0000u);
        a2l += __uint_as_float(u2 << 16); a2h += __uint_as_float(u2 & 0xffff0000u);
        a3l += __uint_as_float(u3 << 16); a3h += __uint_as_float(u3 & 0xffff0000u);
        a0l += __uint_as_float(u4 << 16); a0h += __uint_as_float(u4 & 0xffff0000u);
        a1l += __uint_as_float(u5 << 16); a1h += __uint_as_float(u5 & 0xffff0000u);
        a2l += __uint_as_float(u6 << 16); a2h += __uint_as_float(u6 & 0xffff0000u);
        a3l += __uint_as_float(u7 << 16); a3h += __uint_as_float(u7 & 0xffff0000u);
    }
    // 8-edge tail
    for (; e + 8 <= rp1; e += 8) {
        const ushort2* q = (const ushort2*)(cs + e) + 2 * h2;
        ushort2 p0 = q[0], p1 = q[1];
        unsigned u0 = xb[(size_t)p0.x * 32 + c];
        unsigned u1 = xb[(size_t)p0.y * 32 + c];
        unsigned u2 = xb[(size_t)p1.x * 32 + c];
        unsigned u3 = xb[(size_t)p1.y * 32 + c];
        a0l += __uint_as_float(u0 << 16); a0h += __uint_as_float(u0 & 0xffff0000u);
        a1l += __uint_as_float(u1 << 16); a1h += __uint_as_float(u1 & 0xffff0000u);
        a2l += __uint_as_float(u2 << 16); a2h += __uint_as_float(u2 & 0xffff0000u);
        a3l += __uint_as_float(u3 << 16); a3h += __uint_as_float(u3 & 0xffff0000u);
    }
    float al = (a0l + a1l) + (a2l + a3l);
    float ah = (a0h + a1h) + (a2h + a3h);
    if (h2 == 0) {
        for (; e < rp1; ++e) {
            unsigned u = xb[(size_t)cs[e] * 32 + c];
            al += __uint_as_float(u << 16);
            ah += __uint_as_float(u & 0xffff0000u);
        }
    }
    al += __shfl_xor(al, 32, 64);
    ah += __shfl_xor(ah, 32, 64);

    float inv = 1.f / (float)(d > 1 ? d : 1);
    if (h2 == 0) {
        unsigned uxi = xb[(size_t)i * 32 + c];
        mean_s[widx][2 * c]     = al * inv;
        mean_s[widx][2 * c + 1] = ah * inv;
        xi_s[widx][2 * c]     = __uint_as_float(uxi << 16);
        xi_s[widx][2 * c + 1] = __uint_as_float(uxi & 0xffff0000u);
    }

    float out = b_l[t * 64 + lane];
    #pragma unroll 4
    for (int k0 = 0; k0 < 64; k0 += 4) {
        f32x4 m4 = *(const f32x4*)&mean_s[widx][k0];
        f32x4 x4 = *(const f32x4*)&xi_s[widx][k0];
        f32x4 l4 = *(const f32x4*)&wl[lane][k0];
        f32x4 r4 = *(const f32x4*)&wr[lane][k0];
        out += m4[0] * l4[0] + m4[1] * l4[1] + m4[2] * l4[2] + m4[3] * l4[3];
        out += x4[0] * r4[0] + x4[1] * r4[1] + x4[2] * r4[2] + x4[3] * r4[3];
    }
    out = fmaxf(out, 0.f);
    if (LAYER == 1) {
        yb[(size_t)t * NN * HH + (size_t)i * 64 + lane] =
            __bfloat16_as_ushort(__float2bfloat16(out));
    } else {
        yf[(size_t)t * NN * HH + (size_t)i * 64 + lane] = out;
    }
}

// ---------------- reconstruction: recon[t] = h2[t] @ Wrec[t]^T + brec[t] ----------------
// FROZEN at the r12/r14 structure with nt-stores (measured 175us; eight store-shape
// variants all plateau at ~3 TB/s or worse — this kernel shape's write ceiling).

__global__ void __launch_bounds__(256) recon_kernel(
        const float* __restrict__ h2f, const short* __restrict__ wrecb,
        const float* __restrict__ brec, float* __restrict__ out) {
    constexpr int NI = (NN + 15) / 16;   // 413 strips
    constexpr int NG = 7;                // col-groups of 1024
    __shared__ float buf[16][260];

    int bid = blockIdx.x;
    int t = bid / (NI * NG);
    int rem = bid % (NI * NG);
    int jg = rem / NI;
    int it = rem % NI;
    int i0 = it * 16;
    int colbase = jg * 1024;
    int nch = (NN - colbase + 255) / 256;
    if (nch > 4) nch = 4;

    int tid = threadIdx.x;
    int lane = tid & 63;
    int w = tid >> 6;
    int r = lane & 15;
    int kb = (lane >> 4) * 8;
    int rbase = (lane >> 4) * 4;

    const float* A = h2f + (size_t)t * NN * HH;
    const short* B = wrecb + (size_t)t * NN * HH;
    const float* br = brec + t * NN;
    size_t obase = (size_t)t * NN * NN;

    f32x4 af0 = *(const f32x4*)(A + (size_t)(i0 + r) * 64 + kb);
    f32x4 af1 = *(const f32x4*)(A + (size_t)(i0 + r) * 64 + kb + 4);
    f32x4 af2 = *(const f32x4*)(A + (size_t)(i0 + r) * 64 + kb + 32);
    f32x4 af3 = *(const f32x4*)(A + (size_t)(i0 + r) * 64 + kb + 36);
    bf16x8 a0, a1;
    #pragma unroll
    for (int q = 0; q < 4; ++q) {
        a0[q]     = (short)__bfloat16_as_ushort(__float2bfloat16(af0[q]));
        a0[q + 4] = (short)__bfloat16_as_ushort(__float2bfloat16(af1[q]));
        a1[q]     = (short)__bfloat16_as_ushort(__float2bfloat16(af2[q]));
        a1[q + 4] = (short)__bfloat16_as_ushort(__float2bfloat16(af3[q]));
    }

    int scol = lane << 2;

    bf16x8 Breg[8];
    float biasreg[4];

    auto loadB = [&](int chunk) {
        int jbase = colbase + chunk * 256 + w * 64;
        #pragma unroll
        for (int jt = 0; jt < 4; ++jt) {
            int j0 = jbase + jt * 16;
            Breg[2 * jt]     = *(const bf16x8*)(B + (size_t)(j0 + r) * 64 + kb);
            Breg[2 * jt + 1] = *(const bf16x8*)(B + (size_t)(j0 + r) * 64 + kb + 32);
            int col = j0 + r;
            col = col < NN ? col : NN - 1;
            biasreg[jt] = br[col];
        }
    };

    auto mfma_phase = [&]() {
        #pragma unroll
        for (int jt = 0; jt < 4; ++jt) {
            float bb = biasreg[jt];
            f32x4 acc = {bb, bb, bb, bb};
            acc = __builtin_amdgcn_mfma_f32_16x16x32_bf16(a0, Breg[2 * jt], acc, 0, 0, 0);
            acc = __builtin_amdgcn_mfma_f32_16x16x32_bf16(a1, Breg[2 * jt + 1], acc, 0, 0, 0);
            int jloc = w * 64 + jt * 16 + r;
            #pragma unroll
            for (int q = 0; q < 4; ++q) buf[rbase + q][jloc] = acc[q];
        }
    };

    auto store_phase = [&](int chunk) {
        int colg = colbase + chunk * 256 + scol;
        if (colg >= NN) return;
        bool full4 = (colg + 4 <= NN);
        #pragma unroll
        for (int p = 0; p < 4; ++p) {
            int rloc = p * 4 + w;
            int row = i0 + rloc;
            if (row >= NN) continue;
            f32x4 v = *(const f32x4*)&buf[rloc][scol];
            float* pp = out + obase + (size_t)row * NN + colg;
            if (full4) {
                __builtin_nontemporal_store(v, (f32x4*)pp);
            } else {
                __builtin_nontemporal_store(v[0], pp);
                if (colg + 1 < NN) __builtin_nontemporal_store(v[1], pp + 1);
                if (colg + 2 < NN) __builtin_nontemporal_store(v[2], pp + 2);
            }
        }
    };

    loadB(0);
    mfma_phase();
    LGKM_BARRIER();
    for (int cch = 1; cch < nch; ++cch) {
        loadB(cch);
        store_phase(cch - 1);
        LGKM_BARRIER();
        mfma_phase();
        LGKM_BARRIER();
    }
    store_phase(nch - 1);
}

// ---------------- launch ----------------

extern "C" void kernel_launch(void* const* d_in, const int* in_sizes, int n_in,
                              void* d_out, int out_size, void* d_ws, size_t ws_size,
                              hipStream_t stream) {
    const float* emb  = (const float*)d_in[0];
    const int*   ei   = (const int*)d_in[1];
    const float* W1l  = (const float*)d_in[2];
    const float* b1   = (const float*)d_in[3];
    const float* W1r  = (const float*)d_in[4];
    const float* W2l  = (const float*)d_in[5];
    const float* b2   = (const float*)d_in[6];
    const float* W2r  = (const float*)d_in[7];
    const float* Wrec = (const float*)d_in[8];
    const float* brec = (const float*)d_in[9];

    char* ws = (char*)d_ws;
    int*            degI  = (int*)(ws + 0);            // 79284 -> pad 79296
    int*            basep = (int*)(ws + 79296);        // 79284 -> pad 79296
    unsigned short* csrb  = (unsigned short*)(ws + 158592);   // 6000000 -> 6158592
    unsigned short* H     = (unsigned short*)(ws + 6158592);  // 1982100 -> pad 1982208 -> 8140800
    unsigned short* h1b   = (unsigned short*)(ws + 8140800);  // 2537088 -> 10677888
    short*          embb  = (short*)(ws + 10677888);   // 845696 -> 11523584
    short*          wrecb = (short*)(ws + 11523584);   // 2545280 -> 14068864

    float* o_emb   = (float*)d_out;                        // [T][N][H]
    float* o_recon = o_emb + (size_t)TT * NN * HH;         // [T][N][N]
    float* o_xinit = o_recon + (size_t)TT * NN * NN;       // [N][H]

    int phgrid = KSH * TT + (317136 + 1023) / 1024;   // 150 hist + 310 prep
    prep_hist_kernel<<<phgrid, 1024, 0, stream>>>(Wrec, wrecb, emb, o_xinit, embb, ei, H);
    dim3 o2grid((NN + 255) / 256, TT);                // 26 x 3
    off2a_kernel<<<o2grid, 256, 0, stream>>>(H, degI);
    off2b_kernel<<<TT, 64, 0, stream>>>(degI, basep);
    dim3 fgrid(KSH, TT);
    fill3_kernel<<<fgrid, 1024, 0, stream>>>(ei, H, basep, csrb);

    dim3 sgrid((NN + 7) / 8, TT);                     // 826 x 3, 512-thread blocks
    sage_kernel<1><<<sgrid, 512, 0, stream>>>((const unsigned int*)embb, basep, degI, csrb,
                                              W1l, b1, W1r, nullptr, h1b);
    sage_kernel<2><<<sgrid, 512, 0, stream>>>((const unsigned int*)h1b, basep, degI, csrb,
                                              W2l, b2, W2r, o_emb, nullptr);

    constexpr int NI = (NN + 15) / 16;   // 413
    constexpr int NG = 7;
    int rblocks = NI * NG * TT;          // 8673
    recon_kernel<<<rblocks, 256, 0, stream>>>(o_emb, wrecb, brec, o_recon);
}